// Round 4
// baseline (191.860 us; speedup 1.0000x reference)
//
#include <hip/hip_runtime.h>

#define NN 35

// packed fp32 helpers (v_pk_fma_f32)
typedef float v2f __attribute__((ext_vector_type(2)));

__device__ __forceinline__ v2f pk_fma(v2f a, v2f b, v2f c) {
#if __has_builtin(__builtin_elementwise_fma)
    return __builtin_elementwise_fma(a, b, c);
#else
    v2f d; d.x = fmaf(a.x, b.x, c.x); d.y = fmaf(a.y, b.y, c.y); return d;
#endif
}
__device__ __forceinline__ v2f pk_relu(v2f a) {
    v2f d; d.x = fmaxf(a.x, 0.f); d.y = fmaxf(a.y, 0.f); return d;
}
__device__ __forceinline__ v2f pk_splat(float s) { v2f d; d.x = s; d.y = s; return d; }
__device__ __forceinline__ v2f pk_make(float a, float b) { v2f d; d.x = a; d.y = b; return d; }

__device__ __forceinline__ float agld(const float* p) {
    return __hip_atomic_load(p, __ATOMIC_RELAXED, __HIP_MEMORY_SCOPE_AGENT);
}

// ws layout (floats): agg2[35*256]=8960 | agg3[35*128]=4480 | cnt(1u) | pad(3) | h1[35*512]
// offsets:            0                 | 8960              | 13440   |        | 13444

// ---------------- Kernel 1: layer 1 (1 -> 512) + zero agg2/agg3/cnt ----------------
__global__ __launch_bounds__(512)
void layer1_kernel(const float* __restrict__ x,      // [35,1]
                   const float* __restrict__ ea,     // [1190,4]
                   const float* __restrict__ W1, const float* __restrict__ b1,
                   const float* __restrict__ root1, const float* __restrict__ bias1,
                   float* __restrict__ h1,           // [35,512]
                   float* __restrict__ aggz)         // ws base: agg2|agg3|cnt
{
    const int d = blockIdx.x;
    const int o = threadIdx.x;
    const int gtid = d * 512 + o;
    if (gtid < 35 * 384) aggz[gtid] = 0.f;                 // agg2 + agg3
    if (gtid == 35 * 384) ((unsigned*)aggz)[13440] = 0u;   // done-counter

    const float w0 = W1[o], w1 = W1[512 + o], w2 = W1[1024 + o], w3 = W1[1536 + o];
    const float bb = b1[o];
    float sum = 0.f;
#pragma unroll
    for (int s = 0; s < NN; ++s) {
        if (s == d) continue;
        const float4 a = ((const float4*)ea)[s * 34 + (d < s ? d : d - 1)];
        float w = fmaf(a.x, w0, fmaf(a.y, w1, fmaf(a.z, w2, fmaf(a.w, w3, bb))));
        sum = fmaf(x[s], fmaxf(w, 0.f), sum);
    }
    h1[gtid] = fmaxf(sum * (1.f / 34.f) + x[d] * root1[o] + bias1[o], 0.f);
}

// ---------------- Kernel 2: layer 2 edge+root, dst-major (R1-proven, verbatim) -------
__global__ __launch_bounds__(256, 2)
void edge2_kernel(const float* __restrict__ h,     // [35, 512]
                  const float* __restrict__ ea,    // [1190,4]
                  const float* __restrict__ W,     // [4, 512*256]
                  const float* __restrict__ bias,  // [512*256]
                  const float* __restrict__ root,  // [512, 256]
                  float* __restrict__ agg)         // [35, 256]
{
    const int d  = blockIdx.x;
    const int c  = blockIdx.y;
    const int i0 = c * 16;
    const int o  = threadIdx.x;

    __shared__ __align__(16) float hs[35][16];
    __shared__ float4 as[34];

    if (o < 35) {
        const int s = (o < 34) ? (o + (o >= d ? 1 : 0)) : d;   // row 34 = d itself
        const float4* hp = (const float4*)(h + (size_t)s * 512 + i0);
#pragma unroll
        for (int k = 0; k < 4; ++k) ((float4*)hs[o])[k] = hp[k];
    }
    if (o >= 64 && o < 98) {
        const int j = o - 64;
        const int s = j + (j >= d ? 1 : 0);
        as[j] = ((const float4*)ea)[s * 34 + (d < s ? d : d - 1)];
    }
    __syncthreads();

    v2f Wv0[8], Wv1[8], Wv2[8], Wv3[8], BB[8], RR[8];
#pragma unroll
    for (int p = 0; p < 8; ++p) {
        const size_t b0 = (size_t)(i0 + 2 * p) * 256 + o;
        const size_t bq = b0 + 256;
        Wv0[p] = pk_make(W[b0],          W[bq]);
        Wv1[p] = pk_make(W[131072 + b0], W[131072 + bq]);
        Wv2[p] = pk_make(W[262144 + b0], W[262144 + bq]);
        Wv3[p] = pk_make(W[393216 + b0], W[393216 + bq]);
        BB[p]  = pk_make(bias[b0],       bias[bq]);
        RR[p]  = pk_make(root[b0],       root[bq]);
    }

    v2f acc0 = pk_splat(0.f), acc1 = pk_splat(0.f);
#pragma unroll 2
    for (int j = 0; j < 34; ++j) {
        const float4 a = as[j];
        const v2f ax = pk_splat(a.x), ay = pk_splat(a.y);
        const v2f az = pk_splat(a.z), aw = pk_splat(a.w);
#pragma unroll
        for (int k = 0; k < 2; ++k) {
            const float4 hv = ((const float4*)hs[j])[k * 2];
            const float4 hv2 = ((const float4*)hs[j])[k * 2 + 1];
            {
                const int p = k * 4;
                v2f w = pk_fma(ax, Wv0[p], pk_fma(ay, Wv1[p],
                        pk_fma(az, Wv2[p], pk_fma(aw, Wv3[p], BB[p]))));
                acc0 = pk_fma(pk_make(hv.x, hv.y), pk_relu(w), acc0);
            }
            {
                const int p = k * 4 + 1;
                v2f w = pk_fma(ax, Wv0[p], pk_fma(ay, Wv1[p],
                        pk_fma(az, Wv2[p], pk_fma(aw, Wv3[p], BB[p]))));
                acc1 = pk_fma(pk_make(hv.z, hv.w), pk_relu(w), acc1);
            }
            {
                const int p = k * 4 + 2;
                v2f w = pk_fma(ax, Wv0[p], pk_fma(ay, Wv1[p],
                        pk_fma(az, Wv2[p], pk_fma(aw, Wv3[p], BB[p]))));
                acc0 = pk_fma(pk_make(hv2.x, hv2.y), pk_relu(w), acc0);
            }
            {
                const int p = k * 4 + 3;
                v2f w = pk_fma(ax, Wv0[p], pk_fma(ay, Wv1[p],
                        pk_fma(az, Wv2[p], pk_fma(aw, Wv3[p], BB[p]))));
                acc1 = pk_fma(pk_make(hv2.z, hv2.w), pk_relu(w), acc1);
            }
        }
    }
    v2f racc = pk_splat(0.f);
#pragma unroll
    for (int k = 0; k < 4; ++k) {
        const float4 hv = ((const float4*)hs[34])[k];
        racc = pk_fma(pk_make(hv.x, hv.y), RR[k * 2],     racc);
        racc = pk_fma(pk_make(hv.z, hv.w), RR[k * 2 + 1], racc);
    }
    const float acc = acc0.x + acc0.y + acc1.x + acc1.y;
    atomicAdd(&agg[d * 256 + o], acc * (1.f / 34.f) + (racc.x + racc.y));
}

// ---------------- Kernel 3: layer 3 edge+root (R1 body) + last-block cbt tail --------
__global__ __launch_bounds__(128, 2)
void edge3cbt_kernel(const float* __restrict__ agg2,  // [35, 256] (pre-activation)
                     const float* __restrict__ bias2, // [256]
                     const float* __restrict__ ea,    // [1190,4]
                     const float* __restrict__ W,     // [4, 256*128]
                     const float* __restrict__ bias,  // [256*128]
                     const float* __restrict__ root,  // [256, 128]
                     const float* __restrict__ bias3, // [128]
                     float* __restrict__ agg,         // [35, 128]
                     unsigned* __restrict__ cnt,
                     float* __restrict__ out)         // [35,35]
{
    const int d  = blockIdx.x;
    const int c  = blockIdx.y;
    const int i0 = c * 8;
    const int o  = threadIdx.x;

    __shared__ __align__(16) float hs[35][8];
    __shared__ float4 as[34];
    __shared__ unsigned lastflag;

    if (o < 70) {
        const int r = o >> 1, k = o & 1;
        const int s = (r < 34) ? (r + (r >= d ? 1 : 0)) : d;   // row 34 = d itself
        float4 v = ((const float4*)(agg2 + (size_t)s * 256 + i0))[k];
        const float4 bv = ((const float4*)(bias2 + i0))[k];
        v.x = fmaxf(v.x + bv.x, 0.f);
        v.y = fmaxf(v.y + bv.y, 0.f);
        v.z = fmaxf(v.z + bv.z, 0.f);
        v.w = fmaxf(v.w + bv.w, 0.f);
        ((float4*)hs[r])[k] = v;
    }
    if (o >= 94) {
        const int j = o - 94;
        const int s = j + (j >= d ? 1 : 0);
        as[j] = ((const float4*)ea)[s * 34 + (d < s ? d : d - 1)];
    }
    __syncthreads();

    v2f Wv0[4], Wv1[4], Wv2[4], Wv3[4], BB[4], RR[4];
#pragma unroll
    for (int p = 0; p < 4; ++p) {
        const size_t b0 = (size_t)(i0 + 2 * p) * 128 + o;
        const size_t bq = b0 + 128;
        Wv0[p] = pk_make(W[b0],         W[bq]);
        Wv1[p] = pk_make(W[32768 + b0], W[32768 + bq]);
        Wv2[p] = pk_make(W[65536 + b0], W[65536 + bq]);
        Wv3[p] = pk_make(W[98304 + b0], W[98304 + bq]);
        BB[p]  = pk_make(bias[b0],      bias[bq]);
        RR[p]  = pk_make(root[b0],      root[bq]);
    }

    v2f acc0 = pk_splat(0.f), acc1 = pk_splat(0.f);
#pragma unroll 2
    for (int j = 0; j < 34; ++j) {
        const float4 a = as[j];
        const v2f ax = pk_splat(a.x), ay = pk_splat(a.y);
        const v2f az = pk_splat(a.z), aw = pk_splat(a.w);
#pragma unroll
        for (int k = 0; k < 2; ++k) {
            const float4 hv = ((const float4*)hs[j])[k];
            {
                const int p = k * 2;
                v2f w = pk_fma(ax, Wv0[p], pk_fma(ay, Wv1[p],
                        pk_fma(az, Wv2[p], pk_fma(aw, Wv3[p], BB[p]))));
                acc0 = pk_fma(pk_make(hv.x, hv.y), pk_relu(w), acc0);
            }
            {
                const int p = k * 2 + 1;
                v2f w = pk_fma(ax, Wv0[p], pk_fma(ay, Wv1[p],
                        pk_fma(az, Wv2[p], pk_fma(aw, Wv3[p], BB[p]))));
                acc1 = pk_fma(pk_make(hv.z, hv.w), pk_relu(w), acc1);
            }
        }
    }
    v2f racc = pk_splat(0.f);
#pragma unroll
    for (int k = 0; k < 2; ++k) {
        const float4 hv = ((const float4*)hs[34])[k];
        racc = pk_fma(pk_make(hv.x, hv.y), RR[k * 2],     racc);
        racc = pk_fma(pk_make(hv.z, hv.w), RR[k * 2 + 1], racc);
    }
    const float acc = acc0.x + acc0.y + acc1.x + acc1.y;
    atomicAdd(&agg[d * 128 + o], acc * (1.f / 34.f) + (racc.x + racc.y));

    // ---- last-block cbt tail: out[a,i] = sum_f |relu(agg3+b3)_i - relu(agg3+b3)_a| ----
    __syncthreads();
    if (o == 0) {
        __threadfence();
        lastflag = (atomicAdd(cnt, 1u) == 35u * 32u - 1u) ? 1u : 0u;
    }
    __syncthreads();
    if (!lastflag) return;
    __threadfence();

    for (int idx = o; idx < NN * NN; idx += 128) {
        const int a_ = idx / NN, i_ = idx % NN;
        if (a_ > i_) continue;
        const float* ra = agg + a_ * 128;
        const float* ri = agg + i_ * 128;
        float s = 0.f;
#pragma unroll 16
        for (int f = 0; f < 128; ++f) {
            const float bb = bias3[f];
            const float va = fmaxf(agld(&ra[f]) + bb, 0.f);
            const float vi = fmaxf(agld(&ri[f]) + bb, 0.f);
            s += fabsf(vi - va);
        }
        out[a_ * NN + i_] = s;
        out[i_ * NN + a_] = s;
    }
}

extern "C" void kernel_launch(void* const* d_in, const int* in_sizes, int n_in,
                              void* d_out, int out_size, void* d_ws, size_t ws_size,
                              hipStream_t stream) {
    const float* x      = (const float*)d_in[0];
    const float* ea     = (const float*)d_in[1];
    const float* mlp1_w = (const float*)d_in[3];
    const float* mlp1_b = (const float*)d_in[4];
    const float* root1  = (const float*)d_in[5];
    const float* bias1  = (const float*)d_in[6];
    const float* mlp2_w = (const float*)d_in[7];
    const float* mlp2_b = (const float*)d_in[8];
    const float* root2  = (const float*)d_in[9];
    const float* bias2  = (const float*)d_in[10];
    const float* mlp3_w = (const float*)d_in[11];
    const float* mlp3_b = (const float*)d_in[12];
    const float* root3  = (const float*)d_in[13];
    const float* bias3  = (const float*)d_in[14];
    float* out = (float*)d_out;

    float* ws   = (float*)d_ws;
    float* agg2 = ws;                       // 35*256 = 8960
    float* agg3 = ws + 8960;                // 35*128 = 4480
    unsigned* cnt = (unsigned*)(ws + 13440);
    float* h1   = ws + 13444;               // 35*512

    // 1: layer 1 + zero agg2/agg3/cnt
    layer1_kernel<<<NN, 512, 0, stream>>>(x, ea, mlp1_w, mlp1_b, root1, bias1, h1, ws);
    // 2: layer 2 (512 -> 256)
    edge2_kernel<<<dim3(NN, 32), 256, 0, stream>>>(h1, ea, mlp2_w, mlp2_b, root2, agg2);
    // 3: layer 3 (256 -> 128) + last-block pairwise L1 tail
    edge3cbt_kernel<<<dim3(NN, 32), 128, 0, stream>>>(agg2, bias2, ea, mlp3_w, mlp3_b,
                                                      root3, bias3, agg3, cnt, out);
}

// Round 5
// 157.043 us; speedup vs baseline: 1.2217x; 1.2217x over previous
//
#include <hip/hip_runtime.h>

#define NN 35

// packed fp32 helpers (v_pk_fma_f32)
typedef float v2f __attribute__((ext_vector_type(2)));

__device__ __forceinline__ v2f pk_fma(v2f a, v2f b, v2f c) {
#if __has_builtin(__builtin_elementwise_fma)
    return __builtin_elementwise_fma(a, b, c);
#else
    v2f d; d.x = fmaf(a.x, b.x, c.x); d.y = fmaf(a.y, b.y, c.y); return d;
#endif
}
__device__ __forceinline__ v2f pk_relu(v2f a) {
    v2f d; d.x = fmaxf(a.x, 0.f); d.y = fmaxf(a.y, 0.f); return d;
}
__device__ __forceinline__ v2f pk_splat(float s) { v2f d; d.x = s; d.y = s; return d; }
__device__ __forceinline__ v2f pk_make(float a, float b) { v2f d; d.x = a; d.y = b; return d; }

__device__ __forceinline__ float agld(const float* p) {
    return __hip_atomic_load(p, __ATOMIC_RELAXED, __HIP_MEMORY_SCOPE_AGENT);
}

// ws layout (floats): agg2[35*256]=8960 | agg3[35*128]=4480 | cnt(1u) | pad(3) | h1[35*512]

// ---------------- Kernel 1: layer 1 (1 -> 512) + zero agg2/agg3/cnt ----------------
__global__ __launch_bounds__(512)
void layer1_kernel(const float* __restrict__ x,      // [35,1]
                   const float* __restrict__ ea,     // [1190,4]
                   const float* __restrict__ W1, const float* __restrict__ b1,
                   const float* __restrict__ root1, const float* __restrict__ bias1,
                   float* __restrict__ h1,           // [35,512]
                   float* __restrict__ aggz)         // ws base: agg2|agg3|cnt
{
    const int d = blockIdx.x;
    const int o = threadIdx.x;
    const int gtid = d * 512 + o;
    if (gtid < 35 * 384) aggz[gtid] = 0.f;                 // agg2 + agg3
    if (gtid == 35 * 384) ((unsigned*)aggz)[13440] = 0u;   // done-counter

    const float w0 = W1[o], w1 = W1[512 + o], w2 = W1[1024 + o], w3 = W1[1536 + o];
    const float bb = b1[o];
    float sum = 0.f;
#pragma unroll
    for (int s = 0; s < NN; ++s) {
        if (s == d) continue;
        const float4 a = ((const float4*)ea)[s * 34 + (d < s ? d : d - 1)];
        float w = fmaf(a.x, w0, fmaf(a.y, w1, fmaf(a.z, w2, fmaf(a.w, w3, bb))));
        sum = fmaf(x[s], fmaxf(w, 0.f), sum);
    }
    h1[gtid] = fmaxf(sum * (1.f / 34.f) + x[d] * root1[o] + bias1[o], 0.f);
}

// ---------------- Kernel 2: layer 2 edge+root, dst-major (R1-proven, verbatim) -------
__global__ __launch_bounds__(256, 2)
void edge2_kernel(const float* __restrict__ h,     // [35, 512]
                  const float* __restrict__ ea,    // [1190,4]
                  const float* __restrict__ W,     // [4, 512*256]
                  const float* __restrict__ bias,  // [512*256]
                  const float* __restrict__ root,  // [512, 256]
                  float* __restrict__ agg)         // [35, 256]
{
    const int d  = blockIdx.x;
    const int c  = blockIdx.y;
    const int i0 = c * 16;
    const int o  = threadIdx.x;

    __shared__ __align__(16) float hs[35][16];
    __shared__ float4 as[34];

    if (o < 35) {
        const int s = (o < 34) ? (o + (o >= d ? 1 : 0)) : d;   // row 34 = d itself
        const float4* hp = (const float4*)(h + (size_t)s * 512 + i0);
#pragma unroll
        for (int k = 0; k < 4; ++k) ((float4*)hs[o])[k] = hp[k];
    }
    if (o >= 64 && o < 98) {
        const int j = o - 64;
        const int s = j + (j >= d ? 1 : 0);
        as[j] = ((const float4*)ea)[s * 34 + (d < s ? d : d - 1)];
    }
    __syncthreads();

    v2f Wv0[8], Wv1[8], Wv2[8], Wv3[8], BB[8], RR[8];
#pragma unroll
    for (int p = 0; p < 8; ++p) {
        const size_t b0 = (size_t)(i0 + 2 * p) * 256 + o;
        const size_t bq = b0 + 256;
        Wv0[p] = pk_make(W[b0],          W[bq]);
        Wv1[p] = pk_make(W[131072 + b0], W[131072 + bq]);
        Wv2[p] = pk_make(W[262144 + b0], W[262144 + bq]);
        Wv3[p] = pk_make(W[393216 + b0], W[393216 + bq]);
        BB[p]  = pk_make(bias[b0],       bias[bq]);
        RR[p]  = pk_make(root[b0],       root[bq]);
    }

    v2f acc0 = pk_splat(0.f), acc1 = pk_splat(0.f);
#pragma unroll 2
    for (int j = 0; j < 34; ++j) {
        const float4 a = as[j];
        const v2f ax = pk_splat(a.x), ay = pk_splat(a.y);
        const v2f az = pk_splat(a.z), aw = pk_splat(a.w);
#pragma unroll
        for (int k = 0; k < 4; ++k) {
            const float4 hv = ((const float4*)hs[j])[k];
            {
                const int p = k * 2;
                v2f w = pk_fma(ax, Wv0[p], pk_fma(ay, Wv1[p],
                        pk_fma(az, Wv2[p], pk_fma(aw, Wv3[p], BB[p]))));
                acc0 = pk_fma(pk_make(hv.x, hv.y), pk_relu(w), acc0);
            }
            {
                const int p = k * 2 + 1;
                v2f w = pk_fma(ax, Wv0[p], pk_fma(ay, Wv1[p],
                        pk_fma(az, Wv2[p], pk_fma(aw, Wv3[p], BB[p]))));
                acc1 = pk_fma(pk_make(hv.z, hv.w), pk_relu(w), acc1);
            }
        }
    }
    v2f racc = pk_splat(0.f);
#pragma unroll
    for (int k = 0; k < 4; ++k) {
        const float4 hv = ((const float4*)hs[34])[k];
        racc = pk_fma(pk_make(hv.x, hv.y), RR[k * 2],     racc);
        racc = pk_fma(pk_make(hv.z, hv.w), RR[k * 2 + 1], racc);
    }
    const float acc = acc0.x + acc0.y + acc1.x + acc1.y;
    atomicAdd(&agg[d * 256 + o], acc * (1.f / 34.f) + (racc.x + racc.y));
}

// ------- Kernel 3: layer 3 edge+root (R1 body) + PARALLEL last-35-blocks cbt tail ----
__global__ __launch_bounds__(128, 2)
void edge3cbt_kernel(const float* __restrict__ agg2,  // [35, 256] (pre-activation)
                     const float* __restrict__ bias2, // [256]
                     const float* __restrict__ ea,    // [1190,4]
                     const float* __restrict__ W,     // [4, 256*128]
                     const float* __restrict__ bias,  // [256*128]
                     const float* __restrict__ root,  // [256, 128]
                     const float* __restrict__ bias3, // [128]
                     float* __restrict__ agg,         // [35, 128]
                     unsigned* __restrict__ cnt,
                     float* __restrict__ out)         // [35,35]
{
    const int d  = blockIdx.x;
    const int c  = blockIdx.y;
    const int i0 = c * 8;
    const int o  = threadIdx.x;

    __shared__ __align__(16) float hs[35][8];
    __shared__ float4 as[34];
    __shared__ unsigned ticket_s;

    if (o < 70) {
        const int r = o >> 1, k = o & 1;
        const int s = (r < 34) ? (r + (r >= d ? 1 : 0)) : d;   // row 34 = d itself
        float4 v = ((const float4*)(agg2 + (size_t)s * 256 + i0))[k];
        const float4 bv = ((const float4*)(bias2 + i0))[k];
        v.x = fmaxf(v.x + bv.x, 0.f);
        v.y = fmaxf(v.y + bv.y, 0.f);
        v.z = fmaxf(v.z + bv.z, 0.f);
        v.w = fmaxf(v.w + bv.w, 0.f);
        ((float4*)hs[r])[k] = v;
    }
    if (o >= 94) {
        const int j = o - 94;
        const int s = j + (j >= d ? 1 : 0);
        as[j] = ((const float4*)ea)[s * 34 + (d < s ? d : d - 1)];
    }
    __syncthreads();

    v2f Wv0[4], Wv1[4], Wv2[4], Wv3[4], BB[4], RR[4];
#pragma unroll
    for (int p = 0; p < 4; ++p) {
        const size_t b0 = (size_t)(i0 + 2 * p) * 128 + o;
        const size_t bq = b0 + 128;
        Wv0[p] = pk_make(W[b0],         W[bq]);
        Wv1[p] = pk_make(W[32768 + b0], W[32768 + bq]);
        Wv2[p] = pk_make(W[65536 + b0], W[65536 + bq]);
        Wv3[p] = pk_make(W[98304 + b0], W[98304 + bq]);
        BB[p]  = pk_make(bias[b0],      bias[bq]);
        RR[p]  = pk_make(root[b0],      root[bq]);
    }

    v2f acc0 = pk_splat(0.f), acc1 = pk_splat(0.f);
#pragma unroll 2
    for (int j = 0; j < 34; ++j) {
        const float4 a = as[j];
        const v2f ax = pk_splat(a.x), ay = pk_splat(a.y);
        const v2f az = pk_splat(a.z), aw = pk_splat(a.w);
#pragma unroll
        for (int k = 0; k < 2; ++k) {
            const float4 hv = ((const float4*)hs[j])[k];
            {
                const int p = k * 2;
                v2f w = pk_fma(ax, Wv0[p], pk_fma(ay, Wv1[p],
                        pk_fma(az, Wv2[p], pk_fma(aw, Wv3[p], BB[p]))));
                acc0 = pk_fma(pk_make(hv.x, hv.y), pk_relu(w), acc0);
            }
            {
                const int p = k * 2 + 1;
                v2f w = pk_fma(ax, Wv0[p], pk_fma(ay, Wv1[p],
                        pk_fma(az, Wv2[p], pk_fma(aw, Wv3[p], BB[p]))));
                acc1 = pk_fma(pk_make(hv.z, hv.w), pk_relu(w), acc1);
            }
        }
    }
    v2f racc = pk_splat(0.f);
#pragma unroll
    for (int k = 0; k < 2; ++k) {
        const float4 hv = ((const float4*)hs[34])[k];
        racc = pk_fma(pk_make(hv.x, hv.y), RR[k * 2],     racc);
        racc = pk_fma(pk_make(hv.z, hv.w), RR[k * 2 + 1], racc);
    }
    const float acc = acc0.x + acc0.y + acc1.x + acc1.y;
    atomicAdd(&agg[d * 128 + o], acc * (1.f / 34.f) + (racc.x + racc.y));

    // ---- parallel cbt tail: last 35 tickets each compute one output row ----
    __syncthreads();
    if (o == 0) {
        __threadfence();                       // release this block's agg adds
        ticket_s = atomicAdd(cnt, 1u);
    }
    __syncthreads();
    const int slot = (int)ticket_s - (NN * 32 - NN);   // 1085
    if (slot < 0) return;

    if (o == 0) {
        while (__hip_atomic_load(cnt, __ATOMIC_ACQUIRE, __HIP_MEMORY_SCOPE_AGENT)
               < (unsigned)(NN * 32))
            __builtin_amdgcn_s_sleep(1);
    }
    __syncthreads();
    __threadfence();                           // all blocks' adds now visible

    const int a_ = slot;                       // output row
    const int lane = o & 63, w = o >> 6;       // 2 waves, 2 features per lane
    const float b0 = bias3[lane], b1 = bias3[64 + lane];
    const float va0 = fmaxf(agld(&agg[a_ * 128 + lane])      + b0, 0.f);
    const float va1 = fmaxf(agld(&agg[a_ * 128 + 64 + lane]) + b1, 0.f);
    for (int i = w; i < NN; i += 2) {          // wave0: even i, wave1: odd i
        const float vi0 = fmaxf(agld(&agg[i * 128 + lane])      + b0, 0.f);
        const float vi1 = fmaxf(agld(&agg[i * 128 + 64 + lane]) + b1, 0.f);
        float s = fabsf(vi0 - va0) + fabsf(vi1 - va1);
#pragma unroll
        for (int off = 32; off > 0; off >>= 1)
            s += __shfl_xor(s, off, 64);
        if (lane == 0) out[a_ * NN + i] = s;
    }
}

extern "C" void kernel_launch(void* const* d_in, const int* in_sizes, int n_in,
                              void* d_out, int out_size, void* d_ws, size_t ws_size,
                              hipStream_t stream) {
    const float* x      = (const float*)d_in[0];
    const float* ea     = (const float*)d_in[1];
    const float* mlp1_w = (const float*)d_in[3];
    const float* mlp1_b = (const float*)d_in[4];
    const float* root1  = (const float*)d_in[5];
    const float* bias1  = (const float*)d_in[6];
    const float* mlp2_w = (const float*)d_in[7];
    const float* mlp2_b = (const float*)d_in[8];
    const float* root2  = (const float*)d_in[9];
    const float* bias2  = (const float*)d_in[10];
    const float* mlp3_w = (const float*)d_in[11];
    const float* mlp3_b = (const float*)d_in[12];
    const float* root3  = (const float*)d_in[13];
    const float* bias3  = (const float*)d_in[14];
    float* out = (float*)d_out;

    float* ws   = (float*)d_ws;
    float* agg2 = ws;                       // 35*256 = 8960
    float* agg3 = ws + 8960;                // 35*128 = 4480
    unsigned* cnt = (unsigned*)(ws + 13440);
    float* h1   = ws + 13444;               // 35*512

    // 1: layer 1 + zero agg2/agg3/cnt
    layer1_kernel<<<NN, 512, 0, stream>>>(x, ea, mlp1_w, mlp1_b, root1, bias1, h1, ws);
    // 2: layer 2 (512 -> 256)
    edge2_kernel<<<dim3(NN, 32), 256, 0, stream>>>(h1, ea, mlp2_w, mlp2_b, root2, agg2);
    // 3: layer 3 (256 -> 128) + parallel last-35-blocks pairwise-L1 tail
    edge3cbt_kernel<<<dim3(NN, 32), 128, 0, stream>>>(agg2, bias2, ea, mlp3_w, mlp3_b,
                                                      root3, bias3, agg3, cnt, out);
}

// Round 6
// 128.394 us; speedup vs baseline: 1.4943x; 1.2231x over previous
//
#include <hip/hip_runtime.h>

#define NN 35

// packed fp32 helpers (v_pk_fma_f32)
typedef float v2f __attribute__((ext_vector_type(2)));

__device__ __forceinline__ v2f pk_fma(v2f a, v2f b, v2f c) {
#if __has_builtin(__builtin_elementwise_fma)
    return __builtin_elementwise_fma(a, b, c);
#else
    v2f d; d.x = fmaf(a.x, b.x, c.x); d.y = fmaf(a.y, b.y, c.y); return d;
#endif
}
__device__ __forceinline__ v2f pk_relu(v2f a) {
    v2f d; d.x = fmaxf(a.x, 0.f); d.y = fmaxf(a.y, 0.f); return d;
}
__device__ __forceinline__ v2f pk_splat(float s) { v2f d; d.x = s; d.y = s; return d; }
__device__ __forceinline__ v2f pk_make(float a, float b) { v2f d; d.x = a; d.y = b; return d; }

// ws layout (floats): agg2[35*256]=8960 | agg3[35*128]=4480 | h1[35*512]

// ---------------- Kernel 1: layer 1 (1 -> 512) + zero agg2/agg3 ----------------
__global__ __launch_bounds__(512)
void layer1_kernel(const float* __restrict__ x,      // [35,1]
                   const float* __restrict__ ea,     // [1190,4]
                   const float* __restrict__ W1, const float* __restrict__ b1,
                   const float* __restrict__ root1, const float* __restrict__ bias1,
                   float* __restrict__ h1,           // [35,512]
                   float* __restrict__ aggz)         // agg2..agg3, 35*384 floats
{
    const int d = blockIdx.x;
    const int o = threadIdx.x;
    const int gtid = d * 512 + o;
    if (gtid < 35 * 384) aggz[gtid] = 0.f;

    const float w0 = W1[o], w1 = W1[512 + o], w2 = W1[1024 + o], w3 = W1[1536 + o];
    const float bb = b1[o];
    float sum = 0.f;
#pragma unroll
    for (int s = 0; s < NN; ++s) {
        if (s == d) continue;
        const float4 a = ((const float4*)ea)[s * 34 + (d < s ? d : d - 1)];
        float w = fmaf(a.x, w0, fmaf(a.y, w1, fmaf(a.z, w2, fmaf(a.w, w3, bb))));
        sum = fmaf(x[s], fmaxf(w, 0.f), sum);
    }
    h1[gtid] = fmaxf(sum * (1.f / 34.f) + x[d] * root1[o] + bias1[o], 0.f);
}

// -------- Kernel 2: layer 2 edge+root, IC=8, grid (35,64) — 2x wave concurrency -----
__global__ __launch_bounds__(256, 2)
void edge2_kernel(const float* __restrict__ h,     // [35, 512]
                  const float* __restrict__ ea,    // [1190,4]
                  const float* __restrict__ W,     // [4, 512*256]
                  const float* __restrict__ bias,  // [512*256]
                  const float* __restrict__ root,  // [512, 256]
                  float* __restrict__ agg)         // [35, 256]
{
    const int d  = blockIdx.x;
    const int c  = blockIdx.y;
    const int i0 = c * 8;
    const int o  = threadIdx.x;

    __shared__ __align__(16) float hs[35][8];
    __shared__ float4 as[34];

    // weight fragments first: their fetch overlaps the staging fetch below
    v2f Wv0[4], Wv1[4], Wv2[4], Wv3[4], BB[4], RR[4];
#pragma unroll
    for (int p = 0; p < 4; ++p) {
        const size_t b0 = (size_t)(i0 + 2 * p) * 256 + o;
        const size_t bq = b0 + 256;
        Wv0[p] = pk_make(W[b0],          W[bq]);
        Wv1[p] = pk_make(W[131072 + b0], W[131072 + bq]);
        Wv2[p] = pk_make(W[262144 + b0], W[262144 + bq]);
        Wv3[p] = pk_make(W[393216 + b0], W[393216 + bq]);
        BB[p]  = pk_make(bias[b0],       bias[bq]);
        RR[p]  = pk_make(root[b0],       root[bq]);
    }

    if (o < 70) {
        const int r = o >> 1, k = o & 1;
        const int s = (r < 34) ? (r + (r >= d ? 1 : 0)) : d;   // row 34 = d itself
        ((float4*)hs[r])[k] = ((const float4*)(h + (size_t)s * 512 + i0))[k];
    }
    if (o >= 70 && o < 104) {
        const int j = o - 70;
        const int s = j + (j >= d ? 1 : 0);
        as[j] = ((const float4*)ea)[s * 34 + (d < s ? d : d - 1)];
    }
    __syncthreads();

    v2f acc0 = pk_splat(0.f), acc1 = pk_splat(0.f);
#pragma unroll 2
    for (int j = 0; j < 34; ++j) {
        const float4 a = as[j];
        const v2f ax = pk_splat(a.x), ay = pk_splat(a.y);
        const v2f az = pk_splat(a.z), aw = pk_splat(a.w);
#pragma unroll
        for (int k = 0; k < 2; ++k) {
            const float4 hv = ((const float4*)hs[j])[k];
            {
                const int p = k * 2;
                v2f w = pk_fma(ax, Wv0[p], pk_fma(ay, Wv1[p],
                        pk_fma(az, Wv2[p], pk_fma(aw, Wv3[p], BB[p]))));
                acc0 = pk_fma(pk_make(hv.x, hv.y), pk_relu(w), acc0);
            }
            {
                const int p = k * 2 + 1;
                v2f w = pk_fma(ax, Wv0[p], pk_fma(ay, Wv1[p],
                        pk_fma(az, Wv2[p], pk_fma(aw, Wv3[p], BB[p]))));
                acc1 = pk_fma(pk_make(hv.z, hv.w), pk_relu(w), acc1);
            }
        }
    }
    v2f racc = pk_splat(0.f);
#pragma unroll
    for (int k = 0; k < 2; ++k) {
        const float4 hv = ((const float4*)hs[34])[k];
        racc = pk_fma(pk_make(hv.x, hv.y), RR[k * 2],     racc);
        racc = pk_fma(pk_make(hv.z, hv.w), RR[k * 2 + 1], racc);
    }
    const float acc = acc0.x + acc0.y + acc1.x + acc1.y;
    atomicAdd(&agg[d * 256 + o], acc * (1.f / 34.f) + (racc.x + racc.y));
}

// -------- Kernel 3: layer 3 edge+root, 256 thr (i-half split) — 2x concurrency ------
__global__ __launch_bounds__(256, 2)
void edge3_kernel(const float* __restrict__ agg2,  // [35, 256] (pre-activation)
                  const float* __restrict__ bias2, // [256]
                  const float* __restrict__ ea,    // [1190,4]
                  const float* __restrict__ W,     // [4, 256*128]
                  const float* __restrict__ bias,  // [256*128]
                  const float* __restrict__ root,  // [256, 128]
                  float* __restrict__ agg)         // [35, 128]
{
    const int d   = blockIdx.x;
    const int c   = blockIdx.y;
    const int i0  = c * 8;
    const int thr = threadIdx.x;
    const int o   = thr & 127;
    const int g   = thr >> 7;         // i-half: 0 -> i0..i0+3, 1 -> i0+4..i0+7

    __shared__ __align__(16) float hs[35][8];
    __shared__ float4 as[34];

    // weight fragments first (overlap with staging)
    v2f Wv0[2], Wv1[2], Wv2[2], Wv3[2], BB[2], RR[2];
#pragma unroll
    for (int p = 0; p < 2; ++p) {
        const size_t b0 = (size_t)(i0 + g * 4 + 2 * p) * 128 + o;
        const size_t bq = b0 + 128;
        Wv0[p] = pk_make(W[b0],         W[bq]);
        Wv1[p] = pk_make(W[32768 + b0], W[32768 + bq]);
        Wv2[p] = pk_make(W[65536 + b0], W[65536 + bq]);
        Wv3[p] = pk_make(W[98304 + b0], W[98304 + bq]);
        BB[p]  = pk_make(bias[b0],      bias[bq]);
        RR[p]  = pk_make(root[b0],      root[bq]);
    }

    if (thr < 70) {
        const int r = thr >> 1, k = thr & 1;
        const int s = (r < 34) ? (r + (r >= d ? 1 : 0)) : d;   // row 34 = d itself
        float4 v = ((const float4*)(agg2 + (size_t)s * 256 + i0))[k];
        const float4 bv = ((const float4*)(bias2 + i0))[k];
        v.x = fmaxf(v.x + bv.x, 0.f);
        v.y = fmaxf(v.y + bv.y, 0.f);
        v.z = fmaxf(v.z + bv.z, 0.f);
        v.w = fmaxf(v.w + bv.w, 0.f);
        ((float4*)hs[r])[k] = v;
    }
    if (thr >= 70 && thr < 104) {
        const int j = thr - 70;
        const int s = j + (j >= d ? 1 : 0);
        as[j] = ((const float4*)ea)[s * 34 + (d < s ? d : d - 1)];
    }
    __syncthreads();

    v2f acc0 = pk_splat(0.f), acc1 = pk_splat(0.f);
#pragma unroll 2
    for (int j = 0; j < 34; ++j) {
        const float4 a = as[j];
        const v2f ax = pk_splat(a.x), ay = pk_splat(a.y);
        const v2f az = pk_splat(a.z), aw = pk_splat(a.w);
        const float4 hv = ((const float4*)hs[j])[g];
        {
            v2f w = pk_fma(ax, Wv0[0], pk_fma(ay, Wv1[0],
                    pk_fma(az, Wv2[0], pk_fma(aw, Wv3[0], BB[0]))));
            acc0 = pk_fma(pk_make(hv.x, hv.y), pk_relu(w), acc0);
        }
        {
            v2f w = pk_fma(ax, Wv0[1], pk_fma(ay, Wv1[1],
                    pk_fma(az, Wv2[1], pk_fma(aw, Wv3[1], BB[1]))));
            acc1 = pk_fma(pk_make(hv.z, hv.w), pk_relu(w), acc1);
        }
    }
    v2f racc = pk_splat(0.f);
    {
        const float4 hv = ((const float4*)hs[34])[g];
        racc = pk_fma(pk_make(hv.x, hv.y), RR[0], racc);
        racc = pk_fma(pk_make(hv.z, hv.w), RR[1], racc);
    }
    const float acc = acc0.x + acc0.y + acc1.x + acc1.y;
    atomicAdd(&agg[d * 128 + o], acc * (1.f / 34.f) + (racc.x + racc.y));
}

// ---------------- Kernel 4: pairwise L1, act3 fused; one wave per pair ----------------
__global__ __launch_bounds__(256)
void cbt_kernel(const float* __restrict__ agg3,  // [35, 128] (pre-activation)
                const float* __restrict__ bias3, // [128]
                float* __restrict__ out)         // [35,35]
{
    const int wv = blockIdx.x * 4 + (threadIdx.x >> 6);
    const int lane = threadIdx.x & 63;
    if (wv >= NN * NN) return;
    const int a_ = wv / NN, i_ = wv % NN;
    float s = 0.f;
#pragma unroll
    for (int q = 0; q < 2; ++q) {
        const int f = lane + q * 64;
        const float bb = bias3[f];
        const float hi = fmaxf(agg3[i_ * 128 + f] + bb, 0.f);
        const float ha = fmaxf(agg3[a_ * 128 + f] + bb, 0.f);
        s += fabsf(hi - ha);
    }
#pragma unroll
    for (int off = 32; off > 0; off >>= 1)
        s += __shfl_xor(s, off, 64);
    if (lane == 0) out[wv] = s;
}

extern "C" void kernel_launch(void* const* d_in, const int* in_sizes, int n_in,
                              void* d_out, int out_size, void* d_ws, size_t ws_size,
                              hipStream_t stream) {
    const float* x      = (const float*)d_in[0];
    const float* ea     = (const float*)d_in[1];
    const float* mlp1_w = (const float*)d_in[3];
    const float* mlp1_b = (const float*)d_in[4];
    const float* root1  = (const float*)d_in[5];
    const float* bias1  = (const float*)d_in[6];
    const float* mlp2_w = (const float*)d_in[7];
    const float* mlp2_b = (const float*)d_in[8];
    const float* root2  = (const float*)d_in[9];
    const float* bias2  = (const float*)d_in[10];
    const float* mlp3_w = (const float*)d_in[11];
    const float* mlp3_b = (const float*)d_in[12];
    const float* root3  = (const float*)d_in[13];
    const float* bias3  = (const float*)d_in[14];
    float* out = (float*)d_out;

    float* ws   = (float*)d_ws;
    float* agg2 = ws;                  // 35*256
    float* agg3 = agg2 + 35 * 256;     // 35*128 (contiguous with agg2)
    float* h1   = agg3 + 35 * 128;     // 35*512

    // 1: layer 1 + zero aggs
    layer1_kernel<<<NN, 512, 0, stream>>>(x, ea, mlp1_w, mlp1_b, root1, bias1, h1, agg2);
    // 2: layer 2 (512 -> 256), IC=8, doubled grid for wave concurrency
    edge2_kernel<<<dim3(NN, 64), 256, 0, stream>>>(h1, ea, mlp2_w, mlp2_b, root2, agg2);
    // 3: layer 3 (256 -> 128), act2 fused, 256 threads (i-half split)
    edge3_kernel<<<dim3(NN, 32), 256, 0, stream>>>(agg2, bias2, ea, mlp3_w, mlp3_b, root3, agg3);
    // 4: pairwise L1, act3 fused (1225 waves)
    cbt_kernel<<<(NN * NN + 3) / 4, 256, 0, stream>>>(agg3, bias3, out);
}